// Round 6
// baseline (206.140 us; speedup 1.0000x reference)
//
#include <hip/hip_runtime.h>
#include <hip/hip_bf16.h>

// LSTM: SEQ=64, IN=100000, H=50 (4H=200 gates)
// x[64,100000] f32, Wi[100000,200] f32, bi[200], Wh[50,200], bh[200] -> h[50]
//
// K1: split-K GEMM via MFMA 32x32x16 bf16, hi/lo-split fp32 emulation.
//     R9: dual register sets A/B, double LDS buffer, 1 barrier/tile.
//     R13: RAW BARRIER (T3/T4-lite). __syncthreads() emits
//     `s_waitcnt vmcnt(0) lgkmcnt(0)` before s_barrier (compiler rule),
//     which drained the t+2/t+3 prefetch loads EVERY TILE — the R9
//     pipeline never pipelined across barriers (k1 ~45us at 2.4 TB/s vs
//     18us BW floor). Replace with lgkmcnt(0) + raw s_barrier +
//     sched_barrier(0): LDS ordering fully preserved (lgkmcnt covers
//     ds reads+writes, barrier makes it collective), vmem prefetches stay
//     in flight; data-dep vmcnt at stage waits only its own regset.
// K23 (fused): 200 blocks run the K2 reduce; last block (ticket) runs the
//     LSTM. R13: SINGLE-WAVE REGISTER LSTM. R10/R11/R12 all measured
//     48.0us across 3 different inner loops (incl. spill-free 88-VGPR) —
//     the cost is the per-step sync fabric (64 x barrier-drain + 4 LDS
//     round trips), not FMAs. New: lane l<50 owns gates {l,50+l,100+l,
//     150+l}; Wh columns in ~200 VGPRs; h broadcast via compile-time
//     v_readlane (no LDS, no barriers, no shuffle-permute); gates
//     prefetched 1 step ahead (L2-hot). Bit-identical association: per
//     gate the R0 4-chain split (a0 seeded, j mod 4, 48/49 tail in a0/a1,
//     (a0+a1)+(a2+a3)), identical activation formula order.

#define K_DIM 100000
#define NG 200
#define NS 64
#define TK 32                    // 100000 = 32 * 3125 exactly
#define NBLK 256
#define NTILES 3125              // K_DIM / TK
#define CELLS (NS * NG)          // 12800
#define CELLS4 (CELLS / 4)       // 3200
#define ROWU 40                  // u16 per LDS row = 32 k + 8 pad = 80 B (16B-aligned)
#define K2BLKS (CELLS4 / 16)     // 200

typedef unsigned short u16;
typedef unsigned int   u32;
typedef __bf16 bf16x8 __attribute__((ext_vector_type(8)));
typedef float  f32x16 __attribute__((ext_vector_type(16)));

// raw workgroup barrier WITHOUT the compiler's vmcnt(0) drain:
// own LDS ops retired (lgkmcnt incl. ds_read+ds_write), collective via
// s_barrier; sched_barrier(0) fences the compiler from hoisting the next
// iteration's ds ops above it. Global prefetch loads stay outstanding.
#define TILE_BARRIER() do {                                   \
    asm volatile("s_waitcnt lgkmcnt(0)" ::: "memory");        \
    __builtin_amdgcn_s_barrier();                             \
    __builtin_amdgcn_sched_barrier(0);                        \
} while (0)

static __device__ __forceinline__ u32 rne16(float f) {
    u32 u = __float_as_uint(f);
    return (u + 0x7FFFu + ((u >> 16) & 1u)) >> 16;
}
static __device__ __forceinline__ void split_hl(float f, u32& h, u32& l) {
    u32 u  = __float_as_uint(f);
    u32 hb = u & 0xFFFF0000u;
    h = hb >> 16;
    l = rne16(f - __uint_as_float(hb));   // remainder exact; rne to bf16
}
static __device__ __forceinline__ void split4(float4 v, u32 h[4], u32 l[4]) {
    split_hl(v.x, h[0], l[0]); split_hl(v.y, h[1], l[1]);
    split_hl(v.z, h[2], l[2]); split_hl(v.w, h[3], l[3]);
}
static __device__ __forceinline__ f32x16 mfma_bf(uint4 a, uint4 b, f32x16 c) {
    return __builtin_amdgcn_mfma_f32_32x32x16_bf16(
        __builtin_bit_cast(bf16x8, a), __builtin_bit_cast(bf16x8, b), c, 0, 0, 0);
}
// broadcast lane j's value of v to all lanes (j compile-time; ignores exec)
static __device__ __forceinline__ float rl(float v, int j) {
    return __int_as_float(__builtin_amdgcn_readlane(__float_as_int(v), j));
}

__global__ __launch_bounds__(512, 1) void k1_gemm_partial(
    const float* __restrict__ x, const float* __restrict__ Wi,
    float* __restrict__ partial, unsigned int* __restrict__ ticket)
{
    // double-buffered tiles: 2 x 46 KB = 92 KB LDS (1 block/CU either way)
    __shared__ __align__(16) u16 WH[2][224 * ROWU];   // Wi hi, [g][k]
    __shared__ __align__(16) u16 WL[2][224 * ROWU];   // Wi lo
    __shared__ __align__(16) u16 XH[2][64 * ROWU];    // x  hi, [s][k]
    __shared__ __align__(16) u16 XL[2][64 * ROWU];    // x  lo

    const int t    = threadIdx.x;
    const int lane = t & 63;
    const int wave = t >> 6;             // 0..7
    const int m    = lane & 31;          // MFMA row/col within tile
    const int h    = lane >> 5;          // k-half
    const int stile = wave >> 2;         // 0..1
    const int gset  = wave & 3;          // g-tiles {2g, 2g+1}; gset3: {6, dup6}

    // reset the K23 completion ticket (poisoned ws; K23 runs after us on the
    // same stream, so ordering is guaranteed; re-done every launch/replay)
    if (blockIdx.x == 0 && t == 0) *ticket = 0u;

    // zero Wi pad rows 200..223 once, both buffers
#pragma unroll
    for (int b = 0; b < 2; ++b) {
        u32* zh = (u32*)&WH[b][200 * ROWU];
        u32* zl = (u32*)&WL[b][200 * ROWU];
        for (int i = t; i < 24 * ROWU / 2; i += 512) { zh[i] = 0; zl[i] = 0; }
    }

    // Wi staging: 400 f4-tasks (g4 0..49 x k4 0..7), threads t<400
    const int a_g4 = t >> 3;
    const int a_k4 = t & 7;
    const bool has_w = (t < 400);
    // x staging: 512 f4-tasks (s 0..63 x k4 0..7), one per thread
    const int xs0 = t >> 3, xk0 = t & 7;

    auto do_loads = [&](int ti, float4 (&wr)[4], float4& xr) {
        const size_t kt = (size_t)ti * TK;
        if (has_w) {
#pragma unroll
            for (int j = 0; j < 4; ++j)
                wr[j] = *(const float4*)(Wi + (kt + a_k4 * 4 + j) * NG + a_g4 * 4);
        }
        xr = *(const float4*)(x + (size_t)xs0 * K_DIM + kt + xk0 * 4);
    };
    auto stage_wi = [&](const float4 (&r)[4], u16* WHp, u16* WLp) {
        u32 hw[4][4], lw[4][4];
#pragma unroll
        for (int j = 0; j < 4; ++j) split4(r[j], hw[j], lw[j]);
#pragma unroll
        for (int j2 = 0; j2 < 4; ++j2) {   // transpose: row g=4g4+j2 gets 4 k's
            int off = (4 * a_g4 + j2) * ROWU + a_k4 * 4;
            *(uint2*)&WHp[off] = make_uint2(hw[0][j2] | (hw[1][j2] << 16),
                                            hw[2][j2] | (hw[3][j2] << 16));
            *(uint2*)&WLp[off] = make_uint2(lw[0][j2] | (lw[1][j2] << 16),
                                            lw[2][j2] | (lw[3][j2] << 16));
        }
    };
    auto stage_x = [&](float4 v, u16* XHp, u16* XLp) {
        u32 hh[4], ll[4];
        split4(v, hh, ll);
        int off = xs0 * ROWU + xk0 * 4;
        *(uint2*)&XHp[off] = make_uint2(hh[0] | (hh[1] << 16), hh[2] | (hh[3] << 16));
        *(uint2*)&XLp[off] = make_uint2(ll[0] | (ll[1] << 16), ll[2] | (ll[3] << 16));
    };

    f32x16 acc[2];
#pragma unroll
    for (int tt = 0; tt < 2; ++tt)
#pragma unroll
        for (int r = 0; r < 16; ++r) acc[tt][r] = 0.f;

    // fragment LDS offsets (u16 units)
    const int aoff = (stile * 32 + m) * ROWU + h * 8;
    int boff[2];
#pragma unroll
    for (int tt = 0; tt < 2; ++tt) {
        int gt = (gset == 3 && tt == 1) ? 6 : (2 * gset + tt);
        boff[tt] = (gt * 32 + m) * ROWU + h * 8;
    }

    auto mfma_phase = [&](int p) {
        const u16* WHp = WH[p]; const u16* WLp = WL[p];
        const u16* XHp = XH[p]; const u16* XLp = XL[p];
#pragma unroll
        for (int kk = 0; kk < 2; ++kk) {
            uint4 ah = *(const uint4*)&XHp[aoff + kk * 16];
            uint4 al = *(const uint4*)&XLp[aoff + kk * 16];
#pragma unroll
            for (int tt = 0; tt < 2; ++tt) {
                uint4 bh = *(const uint4*)&WHp[boff[tt] + kk * 16];
                uint4 bl = *(const uint4*)&WLp[boff[tt] + kk * 16];
                acc[tt] = mfma_bf(ah, bh, acc[tt]);   // xh*wh
                acc[tt] = mfma_bf(ah, bl, acc[tt]);   // xh*wl
                acc[tt] = mfma_bf(al, bh, acc[tt]);   // xl*wh
            }
        }
    };

    // ---- prologue: A<-t0, B<-t1; stage A->buf0; A<-t2 (all guards trivially
    //      true: ti0+2*NBLK <= 767 < 3125) ----
    float4 waA[4], waB[4];
    float4 xaA, xaB;
    const int ti0 = blockIdx.x;
    do_loads(ti0,            waA, xaA);
    do_loads(ti0 + NBLK,     waB, xaB);
    if (has_w) stage_wi(waA, WH[0], WL[0]);
    stage_x(xaA, XH[0], XL[0]);
    do_loads(ti0 + 2 * NBLK, waA, xaA);
    TILE_BARRIER();

    // ---- main loop: body for tile ti consumes buf[p]; stages the OTHER
    //      regset (tile ti+NBLK) into buf[p^1]; reissues loads for tile
    //      ti+3*NBLK into that same set. Raw barrier keeps those loads in
    //      flight across iterations; stage's own vmcnt waits are data-dep. ----
    int p = 0;
    int ti = ti0;
    while (ti < NTILES) {
        {   // body: compute ti, stage from B
            int tn = ti + NBLK;
            if (tn < NTILES) {
                if (has_w) stage_wi(waB, WH[p ^ 1], WL[p ^ 1]);
                stage_x(xaB, XH[p ^ 1], XL[p ^ 1]);
                int tf = tn + 2 * NBLK;
                if (tf < NTILES) do_loads(tf, waB, xaB);
            }
            mfma_phase(p);
            TILE_BARRIER();
            p ^= 1; ti += NBLK;
        }
        if (ti >= NTILES) break;
        {   // body: compute ti, stage from A
            int tn = ti + NBLK;
            if (tn < NTILES) {
                if (has_w) stage_wi(waA, WH[p ^ 1], WL[p ^ 1]);
                stage_x(xaA, XH[p ^ 1], XL[p ^ 1]);
                int tf = tn + 2 * NBLK;
                if (tf < NTILES) do_loads(tf, waA, xaA);
            }
            mfma_phase(p);
            TILE_BARRIER();
            p ^= 1; ti += NBLK;
        }
    }

    // epilogue: partial[b][s][g]; C/D: col=lane&31, row=(r&3)+8(r>>2)+4h
    float* base = partial + (size_t)blockIdx.x * CELLS;
#pragma unroll
    for (int tt = 0; tt < 2; ++tt) {
        if (gset == 3 && tt == 1) continue;   // duplicate of tile 6
        int g = (2 * gset + tt) * 32 + m;
        if (g < NG) {
#pragma unroll
            for (int r = 0; r < 16; ++r) {
                int srow = stile * 32 + (r & 3) + 8 * (r >> 2) + 4 * h;
                base[srow * NG + g] = acc[tt][r];
            }
        }
    }
}

__global__ __launch_bounds__(512)
__attribute__((amdgpu_waves_per_eu(2, 2)))
void k23_reduce_lstm(
    const float* __restrict__ partial, const float* __restrict__ bi,
    const float* __restrict__ bh, float* __restrict__ gates,
    unsigned int* __restrict__ ticket,
    const float* __restrict__ Wh, float* __restrict__ out)
{
    // ---- phase 1: K2 reduce (200 blocks x 512 threads) ----
    __shared__ float4 red[512];
    const int tid   = threadIdx.x;
    const int fid   = tid & 15;                 // f4-cell within block
    const int slice = tid >> 4;                 // 0..31, each sums 8 b's
    const int g4    = blockIdx.x * 16 + fid;    // 0..3199

    const float4* p4 = (const float4*)partial;
    float4 sum = make_float4(0.f, 0.f, 0.f, 0.f);
#pragma unroll 4
    for (int b = slice * 8; b < slice * 8 + 8; ++b) {
        float4 v = p4[(size_t)b * CELLS4 + g4];
        sum.x += v.x; sum.y += v.y; sum.z += v.z; sum.w += v.w;
    }
    red[tid] = sum;
    __syncthreads();
    if (tid < 16) {
        float4 tot = red[tid];
#pragma unroll
        for (int p = 1; p < 32; ++p) {
            float4 v = red[p * 16 + tid];
            tot.x += v.x; tot.y += v.y; tot.z += v.z; tot.w += v.w;
        }
        int gg = (g4 * 4) % NG;                 // NG%4==0: never wraps mid-f4
        float4 b1 = *(const float4*)(bi + gg);
        float4 b2 = *(const float4*)(bh + gg);
        tot.x += b1.x + b2.x; tot.y += b1.y + b2.y;
        tot.z += b1.z + b2.z; tot.w += b1.w + b2.w;
        ((float4*)gates)[g4] = tot;
    }

    // ---- ticket: last block to finish runs the LSTM ----
    __shared__ unsigned int lastFlag;
    __syncthreads();                 // all gate stores of this block issued
    if (tid == 0) {
        __threadfence();             // release: make our gates visible
        unsigned int old = atomicAdd(ticket, 1u);
        lastFlag = (old == (unsigned)(gridDim.x - 1)) ? 1u : 0u;
    }
    __syncthreads();
    if (!lastFlag) return;
    __threadfence();                 // acquire: see every block's gates

    // ---- phase 2: 64-step LSTM on ONE WAVE, everything in registers ----
    // Lane l<50 owns gates {l, 50+l, 100+l, 150+l} (i,f,g,o of cell l):
    // the c/h update is entirely in-lane. h[j] lives in lane j; broadcast
    // via compile-time v_readlane (ignores exec; only j<50 read). No LDS,
    // no barriers, no shuffles. Bit-identical association to R0: per gate
    // 4 chains over j mod 4, a0 seeded with the gate pre-activation, tail
    // j=48,49 into a0,a1, z=(a0+a1)+(a2+a3); same activation expressions.
    if (tid >= 64) return;
    const int  l  = tid;
    const bool al = (l < 50);
    const int  lc = al ? l : 49;     // idle lanes compute harmlessly on col 49

    // Wh columns in registers: ~200 VGPR (cap is 256 via waves_per_eu(2,2))
    float wI[50], wF[50], wG[50], wO[50];
    {
        const float* Wp = Wh + lc;
#pragma unroll
        for (int j = 0; j < 50; ++j) {
            const float* r = Wp + j * NG;
            wI[j] = r[0]; wF[j] = r[50]; wG[j] = r[100]; wO[j] = r[150];
        }
    }
    const float* gp = gates + lc;
    float gI = gp[0], gF = gp[50], gG = gp[100], gO = gp[150];
    float c = 0.f, h = 0.f;

    for (int s = 0; s < 64; ++s) {
        // prefetch next step's 4 gate pre-activations (L2-hot, hides under
        // this step's ~600-cycle compute; independent of everything below)
        float nI = 0.f, nF = 0.f, nG = 0.f, nO = 0.f;
        if (s < 63) {
            const float* gn = gp + (s + 1) * NG;
            nI = gn[0]; nF = gn[50]; nG = gn[100]; nO = gn[150];
        }

        float aI0 = gI, aI1 = 0.f, aI2 = 0.f, aI3 = 0.f;
        float aF0 = gF, aF1 = 0.f, aF2 = 0.f, aF3 = 0.f;
        float aG0 = gG, aG1 = 0.f, aG2 = 0.f, aG3 = 0.f;
        float aO0 = gO, aO1 = 0.f, aO2 = 0.f, aO3 = 0.f;
#pragma unroll
        for (int j = 0; j < 48; j += 4) {
            float h0 = rl(h, j),     h1 = rl(h, j + 1);
            float h2 = rl(h, j + 2), h3 = rl(h, j + 3);
            aI0 = fmaf(h0, wI[j], aI0);     aI1 = fmaf(h1, wI[j + 1], aI1);
            aI2 = fmaf(h2, wI[j + 2], aI2); aI3 = fmaf(h3, wI[j + 3], aI3);
            aF0 = fmaf(h0, wF[j], aF0);     aF1 = fmaf(h1, wF[j + 1], aF1);
            aF2 = fmaf(h2, wF[j + 2], aF2); aF3 = fmaf(h3, wF[j + 3], aF3);
            aG0 = fmaf(h0, wG[j], aG0);     aG1 = fmaf(h1, wG[j + 1], aG1);
            aG2 = fmaf(h2, wG[j + 2], aG2); aG3 = fmaf(h3, wG[j + 3], aG3);
            aO0 = fmaf(h0, wO[j], aO0);     aO1 = fmaf(h1, wO[j + 1], aO1);
            aO2 = fmaf(h2, wO[j + 2], aO2); aO3 = fmaf(h3, wO[j + 3], aO3);
        }
        {   // tail j=48,49 -> chains 0,1 (exactly R0's float2 tail)
            float h48 = rl(h, 48), h49 = rl(h, 49);
            aI0 = fmaf(h48, wI[48], aI0); aI1 = fmaf(h49, wI[49], aI1);
            aF0 = fmaf(h48, wF[48], aF0); aF1 = fmaf(h49, wF[49], aF1);
            aG0 = fmaf(h48, wG[48], aG0); aG1 = fmaf(h49, wG[49], aG1);
            aO0 = fmaf(h48, wO[48], aO0); aO1 = fmaf(h49, wO[49], aO1);
        }
        float zI = (aI0 + aI1) + (aI2 + aI3);
        float zF = (aF0 + aF1) + (aF2 + aF3);
        float zG = (aG0 + aG1) + (aG2 + aG3);
        float zO = (aO0 + aO1) + (aO2 + aO3);

        // identical expressions to R0's activation block
        float eI = __expf(-zI); float iv = 1.f / (1.f + eI);
        float eF = __expf(-zF); float fv = 1.f / (1.f + eF);
        float eG = __expf(-zG); float e2G = eG * eG;
        float gv = (1.f - e2G) / (1.f + e2G);
        float eO = __expf(-zO); float ov = 1.f / (1.f + eO);

        c = fmaf(fv, c, iv * gv);
        float e2c = __expf(-2.f * c);
        h = ov * (1.f - e2c) / (1.f + e2c);

        gI = nI; gF = nF; gG = nG; gO = nO;
    }
    if (al) out[l] = h;
}

extern "C" void kernel_launch(void* const* d_in, const int* in_sizes, int n_in,
                              void* d_out, int out_size, void* d_ws, size_t ws_size,
                              hipStream_t stream)
{
    const float* x  = (const float*)d_in[0];
    const float* Wi = (const float*)d_in[1];
    const float* bi = (const float*)d_in[2];
    const float* Wh = (const float*)d_in[3];
    const float* bh = (const float*)d_in[4];
    float* out = (float*)d_out;

    float* partial = (float*)d_ws;                    // 256*12800 f32 = 13.1 MB
    float* gates   = partial + (size_t)NBLK * CELLS;  // 12800 f32
    unsigned int* ticket = (unsigned int*)(gates + CELLS);

    k1_gemm_partial<<<NBLK, 512, 0, stream>>>(x, Wi, partial, ticket);
    k23_reduce_lstm<<<K2BLKS, 512, 0, stream>>>(partial, bi, bh, gates,
                                                ticket, Wh, out);
}

// Round 7
// 205.184 us; speedup vs baseline: 1.0047x; 1.0047x over previous
//
#include <hip/hip_runtime.h>
#include <hip/hip_bf16.h>

// LSTM: SEQ=64, IN=100000, H=50 (4H=200 gates)
// x[64,100000] f32, Wi[100000,200] f32, bi[200], Wh[50,200], bh[200] -> h[50]
//
// K1: split-K GEMM via MFMA 32x32x16 bf16, hi/lo-split fp32 emulation.
//     R9: dual register sets A/B, double LDS buffer; R13: raw barrier
//     (lgkmcnt-only + s_barrier + sched_barrier) — measured neutral, kept.
// K23 (fused): 200 blocks run the K2 reduce; last block (ticket) runs the
//     LSTM on ONE WAVE, no barriers, h broadcast via v_readlane.
//     R14: PIN THE WEIGHTS. R13 measured VGPR_Count=116 (<200 live
//     weights) + dur 59.7us: the allocator REMATERIALIZED the invariant
//     weight loads into the step loop (~200 L2 reloads per serial step).
//     Fix: 50 named float4 (wI,wF,wG,wO per j) + keep-alive
//     asm volatile(""::"+v") per component — asm results cannot be
//     rematerialized, forcing true register residency (~236 VGPR < 256
//     cap from waves_per_eu(2,2), proven active in R12/R13).
//     FMA association & activation expressions verbatim from R13 (= R0).

#define K_DIM 100000
#define NG 200
#define NS 64
#define TK 32                    // 100000 = 32 * 3125 exactly
#define NBLK 256
#define NTILES 3125              // K_DIM / TK
#define CELLS (NS * NG)          // 12800
#define CELLS4 (CELLS / 4)       // 3200
#define ROWU 40                  // u16 per LDS row = 32 k + 8 pad = 80 B (16B-aligned)
#define K2BLKS (CELLS4 / 16)     // 200

typedef unsigned short u16;
typedef unsigned int   u32;
typedef __bf16 bf16x8 __attribute__((ext_vector_type(8)));
typedef float  f32x16 __attribute__((ext_vector_type(16)));

// raw workgroup barrier WITHOUT the compiler's vmcnt(0) drain (R13, neutral)
#define TILE_BARRIER() do {                                   \
    asm volatile("s_waitcnt lgkmcnt(0)" ::: "memory");        \
    __builtin_amdgcn_s_barrier();                             \
    __builtin_amdgcn_sched_barrier(0);                        \
} while (0)

static __device__ __forceinline__ u32 rne16(float f) {
    u32 u = __float_as_uint(f);
    return (u + 0x7FFFu + ((u >> 16) & 1u)) >> 16;
}
static __device__ __forceinline__ void split_hl(float f, u32& h, u32& l) {
    u32 u  = __float_as_uint(f);
    u32 hb = u & 0xFFFF0000u;
    h = hb >> 16;
    l = rne16(f - __uint_as_float(hb));   // remainder exact; rne to bf16
}
static __device__ __forceinline__ void split4(float4 v, u32 h[4], u32 l[4]) {
    split_hl(v.x, h[0], l[0]); split_hl(v.y, h[1], l[1]);
    split_hl(v.z, h[2], l[2]); split_hl(v.w, h[3], l[3]);
}
static __device__ __forceinline__ f32x16 mfma_bf(uint4 a, uint4 b, f32x16 c) {
    return __builtin_amdgcn_mfma_f32_32x32x16_bf16(
        __builtin_bit_cast(bf16x8, a), __builtin_bit_cast(bf16x8, b), c, 0, 0, 0);
}
// broadcast lane j's value of v to all lanes (j compile-time; ignores exec)
static __device__ __forceinline__ float rl(float v, int j) {
    return __int_as_float(__builtin_amdgcn_readlane(__float_as_int(v), j));
}

__global__ __launch_bounds__(512, 1) void k1_gemm_partial(
    const float* __restrict__ x, const float* __restrict__ Wi,
    float* __restrict__ partial, unsigned int* __restrict__ ticket)
{
    // double-buffered tiles: 2 x 46 KB = 92 KB LDS (1 block/CU either way)
    __shared__ __align__(16) u16 WH[2][224 * ROWU];   // Wi hi, [g][k]
    __shared__ __align__(16) u16 WL[2][224 * ROWU];   // Wi lo
    __shared__ __align__(16) u16 XH[2][64 * ROWU];    // x  hi, [s][k]
    __shared__ __align__(16) u16 XL[2][64 * ROWU];    // x  lo

    const int t    = threadIdx.x;
    const int lane = t & 63;
    const int wave = t >> 6;             // 0..7
    const int m    = lane & 31;          // MFMA row/col within tile
    const int h    = lane >> 5;          // k-half
    const int stile = wave >> 2;         // 0..1
    const int gset  = wave & 3;          // g-tiles {2g, 2g+1}; gset3: {6, dup6}

    // reset the K23 completion ticket (poisoned ws; K23 runs after us on the
    // same stream, so ordering is guaranteed; re-done every launch/replay)
    if (blockIdx.x == 0 && t == 0) *ticket = 0u;

    // zero Wi pad rows 200..223 once, both buffers
#pragma unroll
    for (int b = 0; b < 2; ++b) {
        u32* zh = (u32*)&WH[b][200 * ROWU];
        u32* zl = (u32*)&WL[b][200 * ROWU];
        for (int i = t; i < 24 * ROWU / 2; i += 512) { zh[i] = 0; zl[i] = 0; }
    }

    // Wi staging: 400 f4-tasks (g4 0..49 x k4 0..7), threads t<400
    const int a_g4 = t >> 3;
    const int a_k4 = t & 7;
    const bool has_w = (t < 400);
    // x staging: 512 f4-tasks (s 0..63 x k4 0..7), one per thread
    const int xs0 = t >> 3, xk0 = t & 7;

    auto do_loads = [&](int ti, float4 (&wr)[4], float4& xr) {
        const size_t kt = (size_t)ti * TK;
        if (has_w) {
#pragma unroll
            for (int j = 0; j < 4; ++j)
                wr[j] = *(const float4*)(Wi + (kt + a_k4 * 4 + j) * NG + a_g4 * 4);
        }
        xr = *(const float4*)(x + (size_t)xs0 * K_DIM + kt + xk0 * 4);
    };
    auto stage_wi = [&](const float4 (&r)[4], u16* WHp, u16* WLp) {
        u32 hw[4][4], lw[4][4];
#pragma unroll
        for (int j = 0; j < 4; ++j) split4(r[j], hw[j], lw[j]);
#pragma unroll
        for (int j2 = 0; j2 < 4; ++j2) {   // transpose: row g=4g4+j2 gets 4 k's
            int off = (4 * a_g4 + j2) * ROWU + a_k4 * 4;
            *(uint2*)&WHp[off] = make_uint2(hw[0][j2] | (hw[1][j2] << 16),
                                            hw[2][j2] | (hw[3][j2] << 16));
            *(uint2*)&WLp[off] = make_uint2(lw[0][j2] | (lw[1][j2] << 16),
                                            lw[2][j2] | (lw[3][j2] << 16));
        }
    };
    auto stage_x = [&](float4 v, u16* XHp, u16* XLp) {
        u32 hh[4], ll[4];
        split4(v, hh, ll);
        int off = xs0 * ROWU + xk0 * 4;
        *(uint2*)&XHp[off] = make_uint2(hh[0] | (hh[1] << 16), hh[2] | (hh[3] << 16));
        *(uint2*)&XLp[off] = make_uint2(ll[0] | (ll[1] << 16), ll[2] | (ll[3] << 16));
    };

    f32x16 acc[2];
#pragma unroll
    for (int tt = 0; tt < 2; ++tt)
#pragma unroll
        for (int r = 0; r < 16; ++r) acc[tt][r] = 0.f;

    // fragment LDS offsets (u16 units)
    const int aoff = (stile * 32 + m) * ROWU + h * 8;
    int boff[2];
#pragma unroll
    for (int tt = 0; tt < 2; ++tt) {
        int gt = (gset == 3 && tt == 1) ? 6 : (2 * gset + tt);
        boff[tt] = (gt * 32 + m) * ROWU + h * 8;
    }

    auto mfma_phase = [&](int p) {
        const u16* WHp = WH[p]; const u16* WLp = WL[p];
        const u16* XHp = XH[p]; const u16* XLp = XL[p];
#pragma unroll
        for (int kk = 0; kk < 2; ++kk) {
            uint4 ah = *(const uint4*)&XHp[aoff + kk * 16];
            uint4 al = *(const uint4*)&XLp[aoff + kk * 16];
#pragma unroll
            for (int tt = 0; tt < 2; ++tt) {
                uint4 bh = *(const uint4*)&WHp[boff[tt] + kk * 16];
                uint4 bl = *(const uint4*)&WLp[boff[tt] + kk * 16];
                acc[tt] = mfma_bf(ah, bh, acc[tt]);   // xh*wh
                acc[tt] = mfma_bf(ah, bl, acc[tt]);   // xh*wl
                acc[tt] = mfma_bf(al, bh, acc[tt]);   // xl*wh
            }
        }
    };

    // ---- prologue: A<-t0, B<-t1; stage A->buf0; A<-t2 ----
    float4 waA[4], waB[4];
    float4 xaA, xaB;
    const int ti0 = blockIdx.x;
    do_loads(ti0,            waA, xaA);
    do_loads(ti0 + NBLK,     waB, xaB);
    if (has_w) stage_wi(waA, WH[0], WL[0]);
    stage_x(xaA, XH[0], XL[0]);
    do_loads(ti0 + 2 * NBLK, waA, xaA);
    TILE_BARRIER();

    int p = 0;
    int ti = ti0;
    while (ti < NTILES) {
        {   // body: compute ti, stage from B
            int tn = ti + NBLK;
            if (tn < NTILES) {
                if (has_w) stage_wi(waB, WH[p ^ 1], WL[p ^ 1]);
                stage_x(xaB, XH[p ^ 1], XL[p ^ 1]);
                int tf = tn + 2 * NBLK;
                if (tf < NTILES) do_loads(tf, waB, xaB);
            }
            mfma_phase(p);
            TILE_BARRIER();
            p ^= 1; ti += NBLK;
        }
        if (ti >= NTILES) break;
        {   // body: compute ti, stage from A
            int tn = ti + NBLK;
            if (tn < NTILES) {
                if (has_w) stage_wi(waA, WH[p ^ 1], WL[p ^ 1]);
                stage_x(xaA, XH[p ^ 1], XL[p ^ 1]);
                int tf = tn + 2 * NBLK;
                if (tf < NTILES) do_loads(tf, waA, xaA);
            }
            mfma_phase(p);
            TILE_BARRIER();
            p ^= 1; ti += NBLK;
        }
    }

    // epilogue: partial[b][s][g]; C/D: col=lane&31, row=(r&3)+8(r>>2)+4h
    float* base = partial + (size_t)blockIdx.x * CELLS;
#pragma unroll
    for (int tt = 0; tt < 2; ++tt) {
        if (gset == 3 && tt == 1) continue;   // duplicate of tile 6
        int g = (2 * gset + tt) * 32 + m;
        if (g < NG) {
#pragma unroll
            for (int r = 0; r < 16; ++r) {
                int srow = stile * 32 + (r & 3) + 8 * (r >> 2) + 4 * h;
                base[srow * NG + g] = acc[tt][r];
            }
        }
    }
}

// repetition helper: F(K) for K = 0..49
#define W_ALL(F) \
    F(0)  F(1)  F(2)  F(3)  F(4)  F(5)  F(6)  F(7)  F(8)  F(9)  \
    F(10) F(11) F(12) F(13) F(14) F(15) F(16) F(17) F(18) F(19) \
    F(20) F(21) F(22) F(23) F(24) F(25) F(26) F(27) F(28) F(29) \
    F(30) F(31) F(32) F(33) F(34) F(35) F(36) F(37) F(38) F(39) \
    F(40) F(41) F(42) F(43) F(44) F(45) F(46) F(47) F(48) F(49)

__global__ __launch_bounds__(512)
__attribute__((amdgpu_waves_per_eu(2, 2)))
void k23_reduce_lstm(
    const float* __restrict__ partial, const float* __restrict__ bi,
    const float* __restrict__ bh, float* __restrict__ gates,
    unsigned int* __restrict__ ticket,
    const float* __restrict__ Wh, float* __restrict__ out)
{
    // ---- phase 1: K2 reduce (200 blocks x 512 threads) ----
    __shared__ float4 red[512];
    const int tid   = threadIdx.x;
    const int fid   = tid & 15;                 // f4-cell within block
    const int slice = tid >> 4;                 // 0..31, each sums 8 b's
    const int g4    = blockIdx.x * 16 + fid;    // 0..3199

    const float4* p4 = (const float4*)partial;
    float4 sum = make_float4(0.f, 0.f, 0.f, 0.f);
#pragma unroll 4
    for (int b = slice * 8; b < slice * 8 + 8; ++b) {
        float4 v = p4[(size_t)b * CELLS4 + g4];
        sum.x += v.x; sum.y += v.y; sum.z += v.z; sum.w += v.w;
    }
    red[tid] = sum;
    __syncthreads();
    if (tid < 16) {
        float4 tot = red[tid];
#pragma unroll
        for (int p = 1; p < 32; ++p) {
            float4 v = red[p * 16 + tid];
            tot.x += v.x; tot.y += v.y; tot.z += v.z; tot.w += v.w;
        }
        int gg = (g4 * 4) % NG;                 // NG%4==0: never wraps mid-f4
        float4 b1 = *(const float4*)(bi + gg);
        float4 b2 = *(const float4*)(bh + gg);
        tot.x += b1.x + b2.x; tot.y += b1.y + b2.y;
        tot.z += b1.z + b2.z; tot.w += b1.w + b2.w;
        ((float4*)gates)[g4] = tot;
    }

    // ---- ticket: last block to finish runs the LSTM ----
    __shared__ unsigned int lastFlag;
    __syncthreads();                 // all gate stores of this block issued
    if (tid == 0) {
        __threadfence();             // release: make our gates visible
        unsigned int old = atomicAdd(ticket, 1u);
        lastFlag = (old == (unsigned)(gridDim.x - 1)) ? 1u : 0u;
    }
    __syncthreads();
    if (!lastFlag) return;
    __threadfence();                 // acquire: see every block's gates

    // ---- phase 2: 64-step LSTM on ONE WAVE, everything in registers ----
    // Lane l<50 owns gates {l, 50+l, 100+l, 150+l}. h[j] lives in lane j,
    // broadcast via compile-time v_readlane. No LDS, no barriers.
    // R14: weights in 50 NAMED float4 regs, pinned by keep-alive asm so the
    // allocator can neither spill-by-remat nor sink the loads into the loop.
    if (tid >= 64) return;
    const int  l  = tid;
    const bool al = (l < 50);
    const int  lc = al ? l : 49;     // idle lanes compute harmlessly on col 49

    const float* Wp = Wh + lc;
    const float* gp = gates + lc;

    // w##K = (wI[K], wF[K], wG[K], wO[K]) = Wh[K][lc + {0,50,100,150}]
#define DECLW(K) float4 w##K;
    W_ALL(DECLW)
#undef DECLW
#define LOADW(K) w##K = make_float4(Wp[(K) * NG],       Wp[(K) * NG + 50], \
                                    Wp[(K) * NG + 100], Wp[(K) * NG + 150]);
    W_ALL(LOADW)
#undef LOADW
    // first two steps' gate pre-activations before pinning (overlap latency)
    float gI = gp[0], gF = gp[50], gG = gp[100], gO = gp[150];
    // pin: asm results are opaque -> must stay in VGPRs, cannot be re-derived
#define KEEPW(K) asm volatile("" : "+v"(w##K.x), "+v"(w##K.y), \
                                   "+v"(w##K.z), "+v"(w##K.w));
    W_ALL(KEEPW)
#undef KEEPW

    float c = 0.f, h = 0.f;

    for (int s = 0; s < 64; ++s) {
        // prefetch next step's 4 gate pre-activations (L2-hot; hides under
        // this step's ~600-cycle compute)
        float nI = 0.f, nF = 0.f, nG = 0.f, nO = 0.f;
        if (s < 63) {
            const float* gn = gp + (s + 1) * NG;
            nI = gn[0]; nF = gn[50]; nG = gn[100]; nO = gn[150];
        }

        float aI0 = gI, aI1 = 0.f, aI2 = 0.f, aI3 = 0.f;
        float aF0 = gF, aF1 = 0.f, aF2 = 0.f, aF3 = 0.f;
        float aG0 = gG, aG1 = 0.f, aG2 = 0.f, aG3 = 0.f;
        float aO0 = gO, aO1 = 0.f, aO2 = 0.f, aO3 = 0.f;

        // chains by j mod 4 (identical association to R0/R13)
#define Q4(A, B, C, D) {                                              \
        float h0 = rl(h, A), h1 = rl(h, B);                           \
        float h2 = rl(h, C), h3 = rl(h, D);                           \
        aI0 = fmaf(h0, w##A.x, aI0); aI1 = fmaf(h1, w##B.x, aI1);     \
        aI2 = fmaf(h2, w##C.x, aI2); aI3 = fmaf(h3, w##D.x, aI3);     \
        aF0 = fmaf(h0, w##A.y, aF0); aF1 = fmaf(h1, w##B.y, aF1);     \
        aF2 = fmaf(h2, w##C.y, aF2); aF3 = fmaf(h3, w##D.y, aF3);     \
        aG0 = fmaf(h0, w##A.z, aG0); aG1 = fmaf(h1, w##B.z, aG1);     \
        aG2 = fmaf(h2, w##C.z, aG2); aG3 = fmaf(h3, w##D.z, aG3);     \
        aO0 = fmaf(h0, w##A.w, aO0); aO1 = fmaf(h1, w##B.w, aO1);     \
        aO2 = fmaf(h2, w##C.w, aO2); aO3 = fmaf(h3, w##D.w, aO3); }
        Q4(0, 1, 2, 3)     Q4(4, 5, 6, 7)     Q4(8, 9, 10, 11)
        Q4(12, 13, 14, 15) Q4(16, 17, 18, 19) Q4(20, 21, 22, 23)
        Q4(24, 25, 26, 27) Q4(28, 29, 30, 31) Q4(32, 33, 34, 35)
        Q4(36, 37, 38, 39) Q4(40, 41, 42, 43) Q4(44, 45, 46, 47)
#undef Q4
        {   // tail j=48,49 -> chains 0,1 (exactly R0's float2 tail)
            float h48 = rl(h, 48), h49 = rl(h, 49);
            aI0 = fmaf(h48, w48.x, aI0); aI1 = fmaf(h49, w49.x, aI1);
            aF0 = fmaf(h48, w48.y, aF0); aF1 = fmaf(h49, w49.y, aF1);
            aG0 = fmaf(h48, w48.z, aG0); aG1 = fmaf(h49, w49.z, aG1);
            aO0 = fmaf(h48, w48.w, aO0); aO1 = fmaf(h49, w49.w, aO1);
        }
        float zI = (aI0 + aI1) + (aI2 + aI3);
        float zF = (aF0 + aF1) + (aF2 + aF3);
        float zG = (aG0 + aG1) + (aG2 + aG3);
        float zO = (aO0 + aO1) + (aO2 + aO3);

        // identical expressions to R0's activation block
        float eI = __expf(-zI); float iv = 1.f / (1.f + eI);
        float eF = __expf(-zF); float fv = 1.f / (1.f + eF);
        float eG = __expf(-zG); float e2G = eG * eG;
        float gv = (1.f - e2G) / (1.f + e2G);
        float eO = __expf(-zO); float ov = 1.f / (1.f + eO);

        c = fmaf(fv, c, iv * gv);
        float e2c = __expf(-2.f * c);
        h = ov * (1.f - e2c) / (1.f + e2c);

        gI = nI; gF = nF; gG = nG; gO = nO;
    }
    if (al) out[l] = h;
}

extern "C" void kernel_launch(void* const* d_in, const int* in_sizes, int n_in,
                              void* d_out, int out_size, void* d_ws, size_t ws_size,
                              hipStream_t stream)
{
    const float* x  = (const float*)d_in[0];
    const float* Wi = (const float*)d_in[1];
    const float* bi = (const float*)d_in[2];
    const float* Wh = (const float*)d_in[3];
    const float* bh = (const float*)d_in[4];
    float* out = (float*)d_out;

    float* partial = (float*)d_ws;                    // 256*12800 f32 = 13.1 MB
    float* gates   = partial + (size_t)NBLK * CELLS;  // 12800 f32
    unsigned int* ticket = (unsigned int*)(gates + CELLS);

    k1_gemm_partial<<<NBLK, 512, 0, stream>>>(x, Wi, partial, ticket);
    k23_reduce_lstm<<<K2BLKS, 512, 0, stream>>>(partial, bi, bh, gates,
                                                ticket, Wh, out);
}

// Round 8
// 177.595 us; speedup vs baseline: 1.1607x; 1.1554x over previous
//
#include <hip/hip_runtime.h>
#include <hip/hip_bf16.h>

// LSTM: SEQ=64, IN=100000, H=50 (4H=200 gates)
// x[64,100000] f32, Wi[100000,200] f32, bi[200], Wh[50,200], bh[200] -> h[50]
//
// R15: revert to the proven 3-kernel R9 skeleton (best measured: 184.8us);
//      fused-ticket variants (R10-R14) were all slower. New k3 only.
//
// K1: split-K GEMM via MFMA 32x32x16 bf16, hi/lo-split fp32 emulation.
//     R9: dual register sets A/B, double LDS buffer; R13 raw barrier kept
//     (lgkmcnt-only; measured neutral).
// K2: reduce 256 partials + bi + bh -> gates[s*200+g]  (verbatim R9).
// K3 (R15): GATE-TYPE-PER-WAVE. 4 waves; wave w owns gate type w
//     (0=i,1=f,2=g,3=o), lane l<50 owns cell l -> 50 weights/lane
//     (register-resident; waves_per_eu(1) raises the VGPR cap — R12/R14
//     proved ~200/lane is unobtainable, 50 is safe). z via intra-wave
//     readlane chain on the wave's own h copy; gates meet through a
//     double-buffered 200-float LDS act[]; c/h updated redundantly in
//     every wave (identical bits) -> ONE lgkmcnt-only barrier per step.
//     Per-gate math verbatim R0 (4 chains by j mod 4, gz seeds a0, tail
//     48/49 -> a0/a1, z=(a0+a1)+(a2+a3); same activation exprs) ->
//     bit-identical output.

#define K_DIM 100000
#define NG 200
#define NS 64
#define TK 32                    // 100000 = 32 * 3125 exactly
#define NBLK 256
#define NTILES 3125              // K_DIM / TK
#define CELLS (NS * NG)          // 12800
#define CELLS4 (CELLS / 4)       // 3200
#define ROWU 40                  // u16 per LDS row = 32 k + 8 pad = 80 B (16B-aligned)

typedef unsigned short u16;
typedef unsigned int   u32;
typedef __bf16 bf16x8 __attribute__((ext_vector_type(8)));
typedef float  f32x16 __attribute__((ext_vector_type(16)));

// raw workgroup barrier WITHOUT the compiler's vmcnt(0) drain:
// own LDS ops retired (lgkmcnt covers ds_read+ds_write), collective via
// s_barrier; sched_barrier(0) stops the compiler hoisting later LDS ops
// above it. Global prefetch loads stay outstanding.
#define TILE_BARRIER() do {                                   \
    asm volatile("s_waitcnt lgkmcnt(0)" ::: "memory");        \
    __builtin_amdgcn_s_barrier();                             \
    __builtin_amdgcn_sched_barrier(0);                        \
} while (0)

static __device__ __forceinline__ u32 rne16(float f) {
    u32 u = __float_as_uint(f);
    return (u + 0x7FFFu + ((u >> 16) & 1u)) >> 16;
}
static __device__ __forceinline__ void split_hl(float f, u32& h, u32& l) {
    u32 u  = __float_as_uint(f);
    u32 hb = u & 0xFFFF0000u;
    h = hb >> 16;
    l = rne16(f - __uint_as_float(hb));   // remainder exact; rne to bf16
}
static __device__ __forceinline__ void split4(float4 v, u32 h[4], u32 l[4]) {
    split_hl(v.x, h[0], l[0]); split_hl(v.y, h[1], l[1]);
    split_hl(v.z, h[2], l[2]); split_hl(v.w, h[3], l[3]);
}
static __device__ __forceinline__ f32x16 mfma_bf(uint4 a, uint4 b, f32x16 c) {
    return __builtin_amdgcn_mfma_f32_32x32x16_bf16(
        __builtin_bit_cast(bf16x8, a), __builtin_bit_cast(bf16x8, b), c, 0, 0, 0);
}
// broadcast lane j's value of v to all lanes (j compile-time; ignores exec)
static __device__ __forceinline__ float rl(float v, int j) {
    return __int_as_float(__builtin_amdgcn_readlane(__float_as_int(v), j));
}

__global__ __launch_bounds__(512, 1) void k1_gemm_partial(
    const float* __restrict__ x, const float* __restrict__ Wi,
    float* __restrict__ partial)
{
    // double-buffered tiles: 2 x 46 KB = 92 KB LDS (1 block/CU either way)
    __shared__ __align__(16) u16 WH[2][224 * ROWU];   // Wi hi, [g][k]
    __shared__ __align__(16) u16 WL[2][224 * ROWU];   // Wi lo
    __shared__ __align__(16) u16 XH[2][64 * ROWU];    // x  hi, [s][k]
    __shared__ __align__(16) u16 XL[2][64 * ROWU];    // x  lo

    const int t    = threadIdx.x;
    const int lane = t & 63;
    const int wave = t >> 6;             // 0..7
    const int m    = lane & 31;          // MFMA row/col within tile
    const int h    = lane >> 5;          // k-half
    const int stile = wave >> 2;         // 0..1
    const int gset  = wave & 3;          // g-tiles {2g, 2g+1}; gset3: {6, dup6}

    // zero Wi pad rows 200..223 once, both buffers
#pragma unroll
    for (int b = 0; b < 2; ++b) {
        u32* zh = (u32*)&WH[b][200 * ROWU];
        u32* zl = (u32*)&WL[b][200 * ROWU];
        for (int i = t; i < 24 * ROWU / 2; i += 512) { zh[i] = 0; zl[i] = 0; }
    }

    // Wi staging: 400 f4-tasks (g4 0..49 x k4 0..7), threads t<400
    const int a_g4 = t >> 3;
    const int a_k4 = t & 7;
    const bool has_w = (t < 400);
    // x staging: 512 f4-tasks (s 0..63 x k4 0..7), one per thread
    const int xs0 = t >> 3, xk0 = t & 7;

    auto do_loads = [&](int ti, float4 (&wr)[4], float4& xr) {
        const size_t kt = (size_t)ti * TK;
        if (has_w) {
#pragma unroll
            for (int j = 0; j < 4; ++j)
                wr[j] = *(const float4*)(Wi + (kt + a_k4 * 4 + j) * NG + a_g4 * 4);
        }
        xr = *(const float4*)(x + (size_t)xs0 * K_DIM + kt + xk0 * 4);
    };
    auto stage_wi = [&](const float4 (&r)[4], u16* WHp, u16* WLp) {
        u32 hw[4][4], lw[4][4];
#pragma unroll
        for (int j = 0; j < 4; ++j) split4(r[j], hw[j], lw[j]);
#pragma unroll
        for (int j2 = 0; j2 < 4; ++j2) {   // transpose: row g=4g4+j2 gets 4 k's
            int off = (4 * a_g4 + j2) * ROWU + a_k4 * 4;
            *(uint2*)&WHp[off] = make_uint2(hw[0][j2] | (hw[1][j2] << 16),
                                            hw[2][j2] | (hw[3][j2] << 16));
            *(uint2*)&WLp[off] = make_uint2(lw[0][j2] | (lw[1][j2] << 16),
                                            lw[2][j2] | (lw[3][j2] << 16));
        }
    };
    auto stage_x = [&](float4 v, u16* XHp, u16* XLp) {
        u32 hh[4], ll[4];
        split4(v, hh, ll);
        int off = xs0 * ROWU + xk0 * 4;
        *(uint2*)&XHp[off] = make_uint2(hh[0] | (hh[1] << 16), hh[2] | (hh[3] << 16));
        *(uint2*)&XLp[off] = make_uint2(ll[0] | (ll[1] << 16), ll[2] | (ll[3] << 16));
    };

    f32x16 acc[2];
#pragma unroll
    for (int tt = 0; tt < 2; ++tt)
#pragma unroll
        for (int r = 0; r < 16; ++r) acc[tt][r] = 0.f;

    // fragment LDS offsets (u16 units)
    const int aoff = (stile * 32 + m) * ROWU + h * 8;
    int boff[2];
#pragma unroll
    for (int tt = 0; tt < 2; ++tt) {
        int gt = (gset == 3 && tt == 1) ? 6 : (2 * gset + tt);
        boff[tt] = (gt * 32 + m) * ROWU + h * 8;
    }

    auto mfma_phase = [&](int p) {
        const u16* WHp = WH[p]; const u16* WLp = WL[p];
        const u16* XHp = XH[p]; const u16* XLp = XL[p];
#pragma unroll
        for (int kk = 0; kk < 2; ++kk) {
            uint4 ah = *(const uint4*)&XHp[aoff + kk * 16];
            uint4 al = *(const uint4*)&XLp[aoff + kk * 16];
#pragma unroll
            for (int tt = 0; tt < 2; ++tt) {
                uint4 bh = *(const uint4*)&WHp[boff[tt] + kk * 16];
                uint4 bl = *(const uint4*)&WLp[boff[tt] + kk * 16];
                acc[tt] = mfma_bf(ah, bh, acc[tt]);   // xh*wh
                acc[tt] = mfma_bf(ah, bl, acc[tt]);   // xh*wl
                acc[tt] = mfma_bf(al, bh, acc[tt]);   // xl*wh
            }
        }
    };

    // ---- prologue: A<-t0, B<-t1; stage A->buf0; A<-t2 ----
    float4 waA[4], waB[4];
    float4 xaA, xaB;
    const int ti0 = blockIdx.x;
    do_loads(ti0,            waA, xaA);
    do_loads(ti0 + NBLK,     waB, xaB);
    if (has_w) stage_wi(waA, WH[0], WL[0]);
    stage_x(xaA, XH[0], XL[0]);
    do_loads(ti0 + 2 * NBLK, waA, xaA);
    TILE_BARRIER();

    int p = 0;
    int ti = ti0;
    while (ti < NTILES) {
        {   // body: compute ti, stage from B
            int tn = ti + NBLK;
            if (tn < NTILES) {
                if (has_w) stage_wi(waB, WH[p ^ 1], WL[p ^ 1]);
                stage_x(xaB, XH[p ^ 1], XL[p ^ 1]);
                int tf = tn + 2 * NBLK;
                if (tf < NTILES) do_loads(tf, waB, xaB);
            }
            mfma_phase(p);
            TILE_BARRIER();
            p ^= 1; ti += NBLK;
        }
        if (ti >= NTILES) break;
        {   // body: compute ti, stage from A
            int tn = ti + NBLK;
            if (tn < NTILES) {
                if (has_w) stage_wi(waA, WH[p ^ 1], WL[p ^ 1]);
                stage_x(xaA, XH[p ^ 1], XL[p ^ 1]);
                int tf = tn + 2 * NBLK;
                if (tf < NTILES) do_loads(tf, waA, xaA);
            }
            mfma_phase(p);
            TILE_BARRIER();
            p ^= 1; ti += NBLK;
        }
    }

    // epilogue: partial[b][s][g]; C/D: col=lane&31, row=(r&3)+8(r>>2)+4h
    float* base = partial + (size_t)blockIdx.x * CELLS;
#pragma unroll
    for (int tt = 0; tt < 2; ++tt) {
        if (gset == 3 && tt == 1) continue;   // duplicate of tile 6
        int g = (2 * gset + tt) * 32 + m;
        if (g < NG) {
#pragma unroll
            for (int r = 0; r < 16; ++r) {
                int srow = stile * 32 + (r & 3) + 8 * (r >> 2) + 4 * h;
                base[srow * NG + g] = acc[tt][r];
            }
        }
    }
}

__global__ __launch_bounds__(512) void k2_reduce(
    const float* __restrict__ partial, const float* __restrict__ bi,
    const float* __restrict__ bh, float* __restrict__ gates)
{
    __shared__ float4 red[512];
    const int tid   = threadIdx.x;
    const int fid   = tid & 15;                 // f4-cell within block
    const int slice = tid >> 4;                 // 0..31, each sums 8 b's
    const int g4    = blockIdx.x * 16 + fid;    // 0..3199

    const float4* p4 = (const float4*)partial;
    float4 sum = make_float4(0.f, 0.f, 0.f, 0.f);
#pragma unroll 4
    for (int b = slice * 8; b < slice * 8 + 8; ++b) {
        float4 v = p4[(size_t)b * CELLS4 + g4];
        sum.x += v.x; sum.y += v.y; sum.z += v.z; sum.w += v.w;
    }
    red[tid] = sum;
    __syncthreads();
    if (tid < 16) {
        float4 tot = red[tid];
#pragma unroll
        for (int p = 1; p < 32; ++p) {
            float4 v = red[p * 16 + tid];
            tot.x += v.x; tot.y += v.y; tot.z += v.z; tot.w += v.w;
        }
        int gg = (g4 * 4) % NG;                 // NG%4==0: never wraps mid-f4
        float4 b1 = *(const float4*)(bi + gg);
        float4 b2 = *(const float4*)(bh + gg);
        tot.x += b1.x + b2.x; tot.y += b1.y + b2.y;
        tot.z += b1.z + b2.z; tot.w += b1.w + b2.w;
        ((float4*)gates)[g4] = tot;
    }
}

__global__ __launch_bounds__(256)
__attribute__((amdgpu_waves_per_eu(1)))
void k3_lstm(
    const float* __restrict__ gates, const float* __restrict__ Wh,
    float* __restrict__ out)
{
    // 4 waves; wave w = gate type (0=i,1=f,2=g,3=o); lane l<50 = cell l.
    // 50 weights/lane in registers (waves_per_eu(1) -> VGPR cap 512; the
    // 116-cap pathology of R13/R14 needed 200/lane — 50 is safe).
    __shared__ float act[2][NG];    // double-buffered by step parity
    const int tid = threadIdx.x;
    const int w   = tid >> 6;       // gate type
    const int l   = tid & 63;
    const bool al = (l < 50);
    const int  lc = al ? l : 49;    // idle lanes compute harmlessly on cell 49
    const int  gidx = w * 50 + lc;  // gate index in [0,200)

    float wv[50];                   // Wh column for this gate: Wh[j][gidx]
#pragma unroll
    for (int j = 0; j < 50; ++j) wv[j] = Wh[j * NG + gidx];

    const float* gp = gates + gidx;
    float gz = gp[0];
    float c = 0.f, h = 0.f;

    for (int s = 0; s < 64; ++s) {
        // prefetch next step's pre-activation (L2-hot; TILE_BARRIER does not
        // drain vmcnt, so this stays in flight under the chain + barrier)
        float nz = (s < 63) ? gp[(s + 1) * NG] : 0.f;

        // z: verbatim R0 association — 4 chains by j mod 4, gz seeds a0,
        // tail j=48,49 -> a0,a1, z=(a0+a1)+(a2+a3). h broadcast intra-wave.
        float a0 = gz, a1 = 0.f, a2 = 0.f, a3 = 0.f;
#pragma unroll
        for (int j = 0; j < 48; j += 4) {
            a0 = fmaf(rl(h, j),     wv[j],     a0);
            a1 = fmaf(rl(h, j + 1), wv[j + 1], a1);
            a2 = fmaf(rl(h, j + 2), wv[j + 2], a2);
            a3 = fmaf(rl(h, j + 3), wv[j + 3], a3);
        }
        a0 = fmaf(rl(h, 48), wv[48], a0);
        a1 = fmaf(rl(h, 49), wv[49], a1);
        float z = (a0 + a1) + (a2 + a3);

        // activation: waves 0,1,3 sigmoid; wave 2 tanh (identical exprs to R0)
        float e = __expf(-z);
        float av;
        if (w == 2) { float e2 = e * e; av = (1.f - e2) / (1.f + e2); }
        else        { av = 1.f / (1.f + e); }
        if (al) act[s & 1][gidx] = av;

        TILE_BARRIER();   // act[s&1] published; lgkmcnt-only (prefetch lives).
        // Race-free: next write to act[s&1] is step s+2, behind barrier(s+1);
        // all step-s readers below finish before passing barrier(s+1).

        // redundant identical c/h update in EVERY wave (same inputs ->
        // same bits) -> no second barrier; h stays wave-local for readlane.
        float iv = act[s & 1][lc];
        float fv = act[s & 1][50 + lc];
        float gv = act[s & 1][100 + lc];
        float ov = act[s & 1][150 + lc];
        c = fmaf(fv, c, iv * gv);
        float e2c = __expf(-2.f * c);
        h = ov * (1.f - e2c) / (1.f + e2c);

        gz = nz;
    }
    if (w == 0 && al) out[l] = h;
}

extern "C" void kernel_launch(void* const* d_in, const int* in_sizes, int n_in,
                              void* d_out, int out_size, void* d_ws, size_t ws_size,
                              hipStream_t stream)
{
    const float* x  = (const float*)d_in[0];
    const float* Wi = (const float*)d_in[1];
    const float* bi = (const float*)d_in[2];
    const float* Wh = (const float*)d_in[3];
    const float* bh = (const float*)d_in[4];
    float* out = (float*)d_out;

    float* partial = (float*)d_ws;                    // 256*12800 f32 = 13.1 MB
    float* gates   = partial + (size_t)NBLK * CELLS;  // 12800 f32

    k1_gemm_partial<<<NBLK, 512, 0, stream>>>(x, Wi, partial);
    k2_reduce<<<CELLS4 / 16, 512, 0, stream>>>(partial, bi, bh, gates);
    k3_lstm<<<1, 256, 0, stream>>>(gates, Wh, out);
}